// Round 2
// baseline (684.093 us; speedup 1.0000x reference)
//
#include <hip/hip_runtime.h>
#include <hip/hip_bf16.h>

typedef __hip_bfloat16 bf16;

__device__ __forceinline__ float b2f(unsigned short u) {
  return __uint_as_float(((unsigned)u) << 16);
}
__device__ __forceinline__ unsigned short f2b(float x) {
  bf16 h = __float2bfloat16(x);
  return *reinterpret_cast<unsigned short*>(&h);
}

// ---------------- dtype probe ----------------
// flag=1: float tensors are bf16 storage. flag=0: fp32 storage.
// fp32 random data: even-index ushorts are float mantissa low-halves -> garbage
// exponents (P(all 128 look sane) ~ 1e-37). fp32 storage of bf16-rounded data:
// even ushorts are all exactly 0. True bf16 N(0,1) data: all sane, nonzero.
__global__ void k_probe(const unsigned short* __restrict__ raw, int* __restrict__ flag) {
  __shared__ int sbad, snz;
  const int t = threadIdx.x;
  if (t == 0) { sbad = 0; snz = 0; }
  __syncthreads();
  const unsigned short u = raw[t];
  const float a = fabsf(b2f(u));
  if (!(a < 100.f)) atomicAdd(&sbad, 1);          // garbage/NaN as bf16
  if (((t & 1) == 0) && u != 0) atomicAdd(&snz, 1);
  __syncthreads();
  if (t == 0) flag[0] = (sbad == 0 && snz > 0) ? 1 : 0;
}

// ---------------- degree / norm ----------------
__global__ void k_degrees(const int* __restrict__ src, const int* __restrict__ dst, int E,
                          int* __restrict__ deg_out, int* __restrict__ deg_in) {
  int i = blockIdx.x * blockDim.x + threadIdx.x;
  int stride = gridDim.x * blockDim.x;
  for (int e = i; e < E; e += stride) {
    atomicAdd(&deg_out[src[e]], 1);
    atomicAdd(&deg_in[dst[e]], 1);
  }
}

__global__ void k_norms(const int* __restrict__ deg_out, const int* __restrict__ deg_in, int N,
                        float* __restrict__ ns, float* __restrict__ nd) {
  int i = blockIdx.x * blockDim.x + threadIdx.x;
  if (i < N) {
    int dov = deg_out[i]; if (dov <= 0) dov = 1;
    int div = deg_in[i];  if (div <= 0) div = 1;
    ns[i] = rsqrtf((float)dov);
    nd[i] = rsqrtf((float)div);
  }
}

// ---------------- exclusive scan over deg_in (chunk=256, <=512 blocks) ----------------
__global__ void k_scan1(const int* __restrict__ deg, int N, int* __restrict__ blockSums) {
  __shared__ int sdata[256];
  int i = blockIdx.x * 256 + threadIdx.x;
  int v = (i < N) ? deg[i] : 0;
  sdata[threadIdx.x] = v;
  __syncthreads();
  for (int s = 128; s > 0; s >>= 1) {
    if (threadIdx.x < s) sdata[threadIdx.x] += sdata[threadIdx.x + s];
    __syncthreads();
  }
  if (threadIdx.x == 0) blockSums[blockIdx.x] = sdata[0];
}

// parallel exclusive scan of block sums (nb <= 512), one block of 512 threads
__global__ void k_scan2(int* __restrict__ blockSums, int nb, int* __restrict__ rowStart,
                        int N, int E) {
  __shared__ int s[512];
  const int t = threadIdx.x;
  const int v = (t < nb) ? blockSums[t] : 0;
  s[t] = v;
  __syncthreads();
  for (int off = 1; off < 512; off <<= 1) {
    int u = (t >= off) ? s[t - off] : 0;
    __syncthreads();
    s[t] += u;
    __syncthreads();
  }
  if (t < nb) blockSums[t] = s[t] - v;  // exclusive
  if (t == 0) rowStart[N] = E;
}

__global__ void k_scan3(const int* __restrict__ deg, const int* __restrict__ blockSums,
                        int* __restrict__ rowStart, int N) {
  __shared__ int sdata[256];
  int i = blockIdx.x * 256 + threadIdx.x;
  int v = (i < N) ? deg[i] : 0;
  sdata[threadIdx.x] = v;
  __syncthreads();
  for (int off = 1; off < 256; off <<= 1) {
    int t = (threadIdx.x >= off) ? sdata[threadIdx.x - off] : 0;
    __syncthreads();
    sdata[threadIdx.x] += t;
    __syncthreads();
  }
  if (i < N) rowStart[i] = blockSums[blockIdx.x] + sdata[threadIdx.x] - v;  // exclusive
}

// ---------------- CSR fill (bucket by dst) ----------------
__global__ void k_fill(const int* __restrict__ src, const int* __restrict__ dst, int E,
                       const int* __restrict__ rowStart, int* __restrict__ cursor,
                       int* __restrict__ edgeSrc) {
  int i = blockIdx.x * blockDim.x + threadIdx.x;
  int stride = gridDim.x * blockDim.x;
  for (int e = i; e < E; e += stride) {
    int d = dst[e];
    int pos = atomicAdd(&cursor[d], 1);
    edgeSrc[rowStart[d] + pos] = src[e];
  }
}

// ---------------- GEMM: out[row][col] = bf16( sum_k (h[row][k]*ns[row]) * W[k][col] ) ----
template <int K, bool FIRST>
__global__ void k_gemm(const void* __restrict__ hin, const float* __restrict__ norm_src,
                       const void* __restrict__ W, const int* __restrict__ flag,
                       int N, unsigned short* __restrict__ out) {
  const bool isb = (*flag != 0);
  __shared__ float sW[K * 64];
  __shared__ float sh[4][K];
  for (int i = threadIdx.x; i < K * 64; i += 256)
    sW[i] = isb ? b2f(((const unsigned short*)W)[i]) : ((const float*)W)[i];
  const int col = threadIdx.x & 63;
  const int r = threadIdx.x >> 6;  // 4 rows per block
  for (int base = blockIdx.x * 4; base < N; base += gridDim.x * 4) {
    const int row = base + r;
    __syncthreads();  // protects sW first use and sh reuse
    if (row < N) {
      const float ns = norm_src[row];
      for (int k = col; k < K; k += 64) {
        float v;
        if (FIRST) {
          v = isb ? b2f(((const unsigned short*)hin)[(size_t)row * K + k])
                  : ((const float*)hin)[(size_t)row * K + k];
        } else {
          v = b2f(((const unsigned short*)hin)[(size_t)row * K + k]);
        }
        sh[r][k] = v * ns;
      }
    }
    __syncthreads();
    if (row < N) {
      float acc = 0.f;
#pragma unroll
      for (int k = 0; k < K; ++k) acc = fmaf(sh[r][k], sW[k * 64 + col], acc);
      out[(size_t)row * 64 + col] = f2b(acc);
    }
  }
}

// ---------------- aggregation: out[n] = relu(nd[n]*sum_{e in CSR[n]} proj[src[e]] + b) ----
// One wave per node; lane = eo*16+cg; eo = parallel edge slot, cg = 4-col group.
template <bool LAST>
__global__ void k_aggregate(const unsigned short* __restrict__ proj,
                            const int* __restrict__ edgeSrc, const int* __restrict__ rowStart,
                            const float* __restrict__ norm_dst, const void* __restrict__ bias,
                            const int* __restrict__ flag, int N, void* __restrict__ outp) {
  const bool isb = (*flag != 0);
  const int lane = threadIdx.x & 63;
  const int eo = lane >> 4;
  const int cg = lane & 15;
  const int wave = (blockIdx.x * blockDim.x + threadIdx.x) >> 6;
  const int nwaves = (gridDim.x * blockDim.x) >> 6;
  float bx, by, bz, bw;
  if (isb) {
    const unsigned short* bb = (const unsigned short*)bias;
    bx = b2f(bb[cg * 4 + 0]); by = b2f(bb[cg * 4 + 1]);
    bz = b2f(bb[cg * 4 + 2]); bw = b2f(bb[cg * 4 + 3]);
  } else {
    const float* bb = (const float*)bias;
    bx = bb[cg * 4 + 0]; by = bb[cg * 4 + 1];
    bz = bb[cg * 4 + 2]; bw = bb[cg * 4 + 3];
  }
  for (int n = wave; n < N; n += nwaves) {
    const int s = rowStart[n];
    const int e = rowStart[n + 1];
    float ax = 0.f, ay = 0.f, az = 0.f, aw = 0.f;
    for (int p = s; p < e; p += 4) {
      const int idx = p + eo;
      if (idx < e) {
        const int sn = edgeSrc[idx];
        const ushort4 v = *(const ushort4*)(proj + (size_t)sn * 64 + (cg << 2));
        ax += b2f(v.x); ay += b2f(v.y); az += b2f(v.z); aw += b2f(v.w);
      }
    }
    ax += __shfl_xor(ax, 16, 64); ay += __shfl_xor(ay, 16, 64);
    az += __shfl_xor(az, 16, 64); aw += __shfl_xor(aw, 16, 64);
    ax += __shfl_xor(ax, 32, 64); ay += __shfl_xor(ay, 32, 64);
    az += __shfl_xor(az, 32, 64); aw += __shfl_xor(aw, 32, 64);
    if (eo == 0) {
      const float nd = norm_dst[n];
      const float rx = fmaxf(fmaf(ax, nd, bx), 0.f);
      const float ry = fmaxf(fmaf(ay, nd, by), 0.f);
      const float rz = fmaxf(fmaf(az, nd, bz), 0.f);
      const float rw = fmaxf(fmaf(aw, nd, bw), 0.f);
      if (LAST && !isb) {
        float4 o; o.x = rx; o.y = ry; o.z = rz; o.w = rw;
        *(float4*)((float*)outp + (size_t)n * 64 + (cg << 2)) = o;
      } else {
        ushort4 o; o.x = f2b(rx); o.y = f2b(ry); o.z = f2b(rz); o.w = f2b(rw);
        *(ushort4*)((unsigned short*)outp + (size_t)n * 64 + (cg << 2)) = o;
      }
    }
  }
}

extern "C" void kernel_launch(void* const* d_in, const int* in_sizes, int n_in,
                              void* d_out, int out_size, void* d_ws, size_t ws_size,
                              hipStream_t stream) {
  const void* features = d_in[0];
  const void* W0 = d_in[1];
  const void* b0 = d_in[2];
  const void* W1 = d_in[3];
  const void* b1 = d_in[4];
  const void* W2 = d_in[5];
  const void* b2 = d_in[6];
  const int* src = (const int*)d_in[7];
  const int* dst = (const int*)d_in[8];
  const int N = in_sizes[0] / 128;
  const int E = in_sizes[7];

  char* w = (char*)d_ws;
  size_t off = 0;
  auto alloc = [&](size_t bytes) {
    void* p = w + off;
    off = (off + bytes + 255) & ~(size_t)255;
    return p;
  };
  int* deg_out = (int*)alloc((size_t)N * 4);
  int* deg_in = (int*)alloc((size_t)N * 4);
  int* cursor = (int*)alloc((size_t)N * 4);
  const size_t zero_bytes = off;  // deg_out + deg_in + cursor must start at 0
  int* flag = (int*)alloc(4);
  int* rowStart = (int*)alloc((size_t)(N + 1) * 4);
  int* blockSums = (int*)alloc(512 * 4);
  float* norm_src = (float*)alloc((size_t)N * 4);
  float* norm_dst = (float*)alloc((size_t)N * 4);
  int* edgeSrc = (int*)alloc((size_t)E * 4);
  unsigned short* projA = (unsigned short*)alloc((size_t)N * 64 * 2);  // bf16
  unsigned short* hB = (unsigned short*)d_out;  // inter-layer h as bf16 scratch in d_out

  hipMemsetAsync(d_ws, 0, zero_bytes, stream);
  k_probe<<<1, 256, 0, stream>>>((const unsigned short*)features, flag);

  k_degrees<<<1024, 256, 0, stream>>>(src, dst, E, deg_out, deg_in);
  k_norms<<<(N + 255) / 256, 256, 0, stream>>>(deg_out, deg_in, N, norm_src, norm_dst);

  const int NB = (N + 255) / 256;
  k_scan1<<<NB, 256, 0, stream>>>(deg_in, N, blockSums);
  k_scan2<<<1, 512, 0, stream>>>(blockSums, NB, rowStart, N, E);
  k_scan3<<<NB, 256, 0, stream>>>(deg_in, blockSums, rowStart, N);
  k_fill<<<1024, 256, 0, stream>>>(src, dst, E, rowStart, cursor, edgeSrc);

  const int AB = (N + 3) / 4;  // one wave (of 4 per block) per node
  // layer 0
  k_gemm<128, true><<<2048, 256, 0, stream>>>(features, norm_src, W0, flag, N, projA);
  k_aggregate<false><<<AB, 256, 0, stream>>>(projA, edgeSrc, rowStart, norm_dst, b0, flag, N, hB);
  // layer 1
  k_gemm<64, false><<<2048, 256, 0, stream>>>(hB, norm_src, W1, flag, N, projA);
  k_aggregate<false><<<AB, 256, 0, stream>>>(projA, edgeSrc, rowStart, norm_dst, b1, flag, N, hB);
  // layer 2 -> d_out (dtype per flag)
  k_gemm<64, false><<<2048, 256, 0, stream>>>(hB, norm_src, W2, flag, N, projA);
  k_aggregate<true><<<AB, 256, 0, stream>>>(projA, edgeSrc, rowStart, norm_dst, b2, flag, N, d_out);
}

// Round 3
// 603.465 us; speedup vs baseline: 1.1336x; 1.1336x over previous
//
#include <hip/hip_runtime.h>
#include <hip/hip_bf16.h>

typedef __hip_bfloat16 bf16;
typedef __attribute__((ext_vector_type(8))) short bf16x8;
typedef __attribute__((ext_vector_type(8))) unsigned short u16x8;
typedef __attribute__((ext_vector_type(4))) float f32x4;

__device__ __forceinline__ float b2f(unsigned short u) {
  return __uint_as_float(((unsigned)u) << 16);
}
__device__ __forceinline__ unsigned short f2b(float x) {
  bf16 h = __float2bfloat16(x);
  return *reinterpret_cast<unsigned short*>(&h);
}

// ---------------- dtype probe (flag=1 -> bf16 storage, 0 -> fp32) ----------------
__global__ void k_probe(const unsigned short* __restrict__ raw, int* __restrict__ flag) {
  __shared__ int sbad, snz;
  const int t = threadIdx.x;
  if (t == 0) { sbad = 0; snz = 0; }
  __syncthreads();
  const unsigned short u = raw[t];
  const float a = fabsf(b2f(u));
  if (!(a < 100.f)) atomicAdd(&sbad, 1);
  if (((t & 1) == 0) && u != 0) atomicAdd(&snz, 1);
  __syncthreads();
  if (t == 0) flag[0] = (sbad == 0 && snz > 0) ? 1 : 0;
}

// ---------------- deg_in histogram ----------------
__global__ void k_deg_in(const int* __restrict__ dst, int E, int* __restrict__ deg_in) {
  int i = blockIdx.x * blockDim.x + threadIdx.x;
  int stride = gridDim.x * blockDim.x;
  for (int e = i; e < E; e += stride) atomicAdd(&deg_in[dst[e]], 1);
}

__global__ void k_norms(const int* __restrict__ deg_out, const int* __restrict__ deg_in, int N,
                        float* __restrict__ ns, float* __restrict__ nd) {
  int i = blockIdx.x * blockDim.x + threadIdx.x;
  if (i < N) {
    int dov = deg_out[i]; if (dov <= 0) dov = 1;
    int div = deg_in[i];  if (div <= 0) div = 1;
    ns[i] = rsqrtf((float)dov);
    nd[i] = rsqrtf((float)div);
  }
}

// ---------------- exclusive scan over deg_in ----------------
__global__ void k_scan1(const int* __restrict__ deg, int N, int* __restrict__ blockSums) {
  __shared__ int sdata[256];
  int i = blockIdx.x * 256 + threadIdx.x;
  int v = (i < N) ? deg[i] : 0;
  sdata[threadIdx.x] = v;
  __syncthreads();
  for (int s = 128; s > 0; s >>= 1) {
    if (threadIdx.x < s) sdata[threadIdx.x] += sdata[threadIdx.x + s];
    __syncthreads();
  }
  if (threadIdx.x == 0) blockSums[blockIdx.x] = sdata[0];
}

__global__ void k_scan2(int* __restrict__ blockSums, int nb, int* __restrict__ rowStart,
                        int N, int E) {
  __shared__ int s[512];
  const int t = threadIdx.x;
  const int v = (t < nb) ? blockSums[t] : 0;
  s[t] = v;
  __syncthreads();
  for (int off = 1; off < 512; off <<= 1) {
    int u = (t >= off) ? s[t - off] : 0;
    __syncthreads();
    s[t] += u;
    __syncthreads();
  }
  if (t < nb) blockSums[t] = s[t] - v;  // exclusive
  if (t == 0) rowStart[N] = E;
}

// writes rowStart AND initializes cursor = rowStart
__global__ void k_scan3(const int* __restrict__ deg, const int* __restrict__ blockSums,
                        int* __restrict__ rowStart, int* __restrict__ cursor, int N) {
  __shared__ int sdata[256];
  int i = blockIdx.x * 256 + threadIdx.x;
  int v = (i < N) ? deg[i] : 0;
  sdata[threadIdx.x] = v;
  __syncthreads();
  for (int off = 1; off < 256; off <<= 1) {
    int t = (threadIdx.x >= off) ? sdata[threadIdx.x - off] : 0;
    __syncthreads();
    sdata[threadIdx.x] += t;
    __syncthreads();
  }
  if (i < N) {
    int rs = blockSums[blockIdx.x] + sdata[threadIdx.x] - v;  // exclusive
    rowStart[i] = rs;
    cursor[i] = rs;
  }
}

// ---------------- CSR fill + deg_out histogram ----------------
__global__ void k_fill(const int* __restrict__ src, const int* __restrict__ dst, int E,
                       int* __restrict__ cursor, int* __restrict__ deg_out,
                       int* __restrict__ edgeSrc) {
  int i = blockIdx.x * blockDim.x + threadIdx.x;
  int stride = gridDim.x * blockDim.x;
  for (int e = i; e < E; e += stride) {
    int sv = src[e];
    int d = dst[e];
    atomicAdd(&deg_out[sv], 1);
    int pos = atomicAdd(&cursor[d], 1);  // absolute slot
    edgeSrc[pos] = sv;
  }
}

// ---------------- MFMA GEMM: out[r][c] = bf16( ns[r] * sum_k h[r][k]*W[k][c] ) ------
// 16x16x32 bf16 MFMA. A frag: A[m=lane&15][k=(lane>>4)*8+j]; B frag: B[k][n=lane&15];
// D: col=lane&15, row=(lane>>4)*4+reg  [m89-verified layouts]
template <int K, bool FIRST>
__global__ void k_gemm(const void* __restrict__ hin, const float* __restrict__ norm_src,
                       const void* __restrict__ Wv, const int* __restrict__ flag,
                       int N, unsigned short* __restrict__ out) {
  const bool isb = (*flag != 0);
  const int lane = threadIdx.x & 63;
  const int quad = lane >> 4;   // 0..3
  const int l16 = lane & 15;
  constexpr int KT = K / 32;

  // B fragments in registers: Bf[kt][nt], W is K x 64 row-major
  bf16x8 Bf[KT][4];
  {
    const unsigned short* Wus = (const unsigned short*)Wv;
    const float* Wf = (const float*)Wv;
#pragma unroll
    for (int kt = 0; kt < KT; ++kt)
#pragma unroll
      for (int nt = 0; nt < 4; ++nt)
#pragma unroll
        for (int j = 0; j < 8; ++j) {
          const int k = kt * 32 + quad * 8 + j;
          const int n = nt * 16 + l16;
          const float w = isb ? b2f(Wus[k * 64 + n]) : Wf[k * 64 + n];
          Bf[kt][nt][j] = (short)f2b(w);
        }
  }

  const int wid = (blockIdx.x * blockDim.x + threadIdx.x) >> 6;
  const int nw = (gridDim.x * blockDim.x) >> 6;
  const int G = (N + 15) >> 4;
  for (int g = wid; g < G; g += nw) {
    int rowA = (g << 4) + l16;
    if (rowA >= N) rowA = N - 1;  // clamp (values for OOB rows never stored)
    f32x4 acc[4] = {{0.f, 0.f, 0.f, 0.f}, {0.f, 0.f, 0.f, 0.f},
                    {0.f, 0.f, 0.f, 0.f}, {0.f, 0.f, 0.f, 0.f}};
#pragma unroll
    for (int kt = 0; kt < KT; ++kt) {
      const int koff = kt * 32 + quad * 8;
      bf16x8 Af;
      if (FIRST && !isb) {
        const float* hp = (const float*)hin + (size_t)rowA * K + koff;
        const float4 u0 = *(const float4*)hp;
        const float4 u1 = *(const float4*)(hp + 4);
        Af[0] = (short)f2b(u0.x); Af[1] = (short)f2b(u0.y);
        Af[2] = (short)f2b(u0.z); Af[3] = (short)f2b(u0.w);
        Af[4] = (short)f2b(u1.x); Af[5] = (short)f2b(u1.y);
        Af[6] = (short)f2b(u1.z); Af[7] = (short)f2b(u1.w);
      } else {
        Af = *(const bf16x8*)((const unsigned short*)hin + (size_t)rowA * K + koff);
      }
      acc[0] = __builtin_amdgcn_mfma_f32_16x16x32_bf16(Af, Bf[kt][0], acc[0], 0, 0, 0);
      acc[1] = __builtin_amdgcn_mfma_f32_16x16x32_bf16(Af, Bf[kt][1], acc[1], 0, 0, 0);
      acc[2] = __builtin_amdgcn_mfma_f32_16x16x32_bf16(Af, Bf[kt][2], acc[2], 0, 0, 0);
      acc[3] = __builtin_amdgcn_mfma_f32_16x16x32_bf16(Af, Bf[kt][3], acc[3], 0, 0, 0);
    }
    const int rowD = (g << 4) + quad * 4;
    float nsv[4];
#pragma unroll
    for (int r = 0; r < 4; ++r) nsv[r] = (rowD + r < N) ? norm_src[rowD + r] : 0.f;
#pragma unroll
    for (int r = 0; r < 4; ++r) {
      if (rowD + r < N) {
        const size_t o = (size_t)(rowD + r) * 64 + l16;
#pragma unroll
        for (int nt = 0; nt < 4; ++nt)
          out[o + nt * 16] = f2b(acc[nt][r] * nsv[r]);
      }
    }
  }
}

// ---------------- aggregation: out[n] = relu(nd[n]*sum proj[src] + b) ----------------
// 1 wave/node. eo=lane>>3 (8 parallel edges), cg=lane&7 (8 cols of 8).
// Edge indices loaded with ONE coalesced 64-wide load, broadcast via shfl.
template <bool LAST>
__global__ void k_aggregate(const unsigned short* __restrict__ proj,
                            const int* __restrict__ edgeSrc, const int* __restrict__ rowStart,
                            const float* __restrict__ norm_dst, const void* __restrict__ bias,
                            const int* __restrict__ flag, int N, void* __restrict__ outp) {
  const bool isb = (*flag != 0);
  const int lane = threadIdx.x & 63;
  const int eo = lane >> 3;
  const int cg = lane & 7;
  float bcol[8];
#pragma unroll
  for (int j = 0; j < 8; ++j)
    bcol[j] = isb ? b2f(((const unsigned short*)bias)[cg * 8 + j])
                  : ((const float*)bias)[cg * 8 + j];
  const int wave = (blockIdx.x * blockDim.x + threadIdx.x) >> 6;
  const int nwaves = (gridDim.x * blockDim.x) >> 6;
  for (int n = wave; n < N; n += nwaves) {
    const int s = rowStart[n];
    int cnt = rowStart[n + 1] - s;
    float a[8] = {0.f, 0.f, 0.f, 0.f, 0.f, 0.f, 0.f, 0.f};
    int base = s;
    while (cnt > 0) {
      const int take = cnt < 64 ? cnt : 64;
      const int myIdx = (lane < take) ? edgeSrc[base + lane] : 0;
      for (int c = 0; c < take; c += 8) {
        const int sl = c + eo;
        const int sn = __shfl(myIdx, sl, 64);
        if (sl < take) {
          const u16x8 v = *(const u16x8*)(proj + (size_t)sn * 64 + cg * 8);
#pragma unroll
          for (int j = 0; j < 8; ++j) a[j] += b2f(v[j]);
        }
      }
      base += take;
      cnt -= take;
    }
#pragma unroll
    for (int j = 0; j < 8; ++j) {
      a[j] += __shfl_xor(a[j], 8, 64);
      a[j] += __shfl_xor(a[j], 16, 64);
      a[j] += __shfl_xor(a[j], 32, 64);
    }
    if (eo == 0) {
      const float nd = norm_dst[n];
      float r[8];
#pragma unroll
      for (int j = 0; j < 8; ++j) r[j] = fmaxf(fmaf(a[j], nd, bcol[j]), 0.f);
      if (LAST && !isb) {
        float* of = (float*)outp + (size_t)n * 64 + cg * 8;
        float4 o0; o0.x = r[0]; o0.y = r[1]; o0.z = r[2]; o0.w = r[3];
        float4 o1; o1.x = r[4]; o1.y = r[5]; o1.z = r[6]; o1.w = r[7];
        *(float4*)of = o0;
        *(float4*)(of + 4) = o1;
      } else {
        u16x8 o;
#pragma unroll
        for (int j = 0; j < 8; ++j) o[j] = f2b(r[j]);
        *(u16x8*)((unsigned short*)outp + (size_t)n * 64 + cg * 8) = o;
      }
    }
  }
}

extern "C" void kernel_launch(void* const* d_in, const int* in_sizes, int n_in,
                              void* d_out, int out_size, void* d_ws, size_t ws_size,
                              hipStream_t stream) {
  const void* features = d_in[0];
  const void* W0 = d_in[1];
  const void* b0 = d_in[2];
  const void* W1 = d_in[3];
  const void* b1 = d_in[4];
  const void* W2 = d_in[5];
  const void* b2 = d_in[6];
  const int* src = (const int*)d_in[7];
  const int* dst = (const int*)d_in[8];
  const int N = in_sizes[0] / 128;
  const int E = in_sizes[7];

  char* w = (char*)d_ws;
  size_t off = 0;
  auto alloc = [&](size_t bytes) {
    void* p = w + off;
    off = (off + bytes + 255) & ~(size_t)255;
    return p;
  };
  int* deg_in = (int*)alloc((size_t)N * 4);
  int* deg_out = (int*)alloc((size_t)N * 4);
  const size_t zero_bytes = off;  // only deg_in + deg_out need zeroing
  int* cursor = (int*)alloc((size_t)N * 4);        // init'd by k_scan3
  int* flag = (int*)alloc(4);
  int* rowStart = (int*)alloc((size_t)(N + 1) * 4);
  int* blockSums = (int*)alloc(512 * 4);
  float* norm_src = (float*)alloc((size_t)N * 4);
  float* norm_dst = (float*)alloc((size_t)N * 4);
  int* edgeSrc = (int*)alloc((size_t)E * 4);
  unsigned short* projA = (unsigned short*)alloc((size_t)N * 64 * 2);  // bf16
  unsigned short* hB = (unsigned short*)d_out;  // inter-layer h (bf16) in d_out

  hipMemsetAsync(d_ws, 0, zero_bytes, stream);
  k_probe<<<1, 256, 0, stream>>>((const unsigned short*)features, flag);

  k_deg_in<<<1024, 256, 0, stream>>>(dst, E, deg_in);

  const int NB = (N + 255) / 256;
  k_scan1<<<NB, 256, 0, stream>>>(deg_in, N, blockSums);
  k_scan2<<<1, 512, 0, stream>>>(blockSums, NB, rowStart, N, E);
  k_scan3<<<NB, 256, 0, stream>>>(deg_in, blockSums, rowStart, cursor, N);
  k_fill<<<1024, 256, 0, stream>>>(src, dst, E, cursor, deg_out, edgeSrc);
  k_norms<<<(N + 255) / 256, 256, 0, stream>>>(deg_out, deg_in, N, norm_src, norm_dst);

  const int GB = ((N + 15) / 16 + 3) / 4;  // 4 waves/block, 1 row-group each
  const int AB = (N + 3) / 4;              // 1 wave/node
  // layer 0
  k_gemm<128, true><<<GB, 256, 0, stream>>>(features, norm_src, W0, flag, N, projA);
  k_aggregate<false><<<AB, 256, 0, stream>>>(projA, edgeSrc, rowStart, norm_dst, b0, flag, N, hB);
  // layer 1
  k_gemm<64, false><<<GB, 256, 0, stream>>>(hB, norm_src, W1, flag, N, projA);
  k_aggregate<false><<<AB, 256, 0, stream>>>(projA, edgeSrc, rowStart, norm_dst, b1, flag, N, hB);
  // layer 2 -> d_out
  k_gemm<64, false><<<GB, 256, 0, stream>>>(hB, norm_src, W2, flag, N, projA);
  k_aggregate<true><<<AB, 256, 0, stream>>>(projA, edgeSrc, rowStart, norm_dst, b2, flag, N, d_out);
}

// Round 4
// 484.808 us; speedup vs baseline: 1.4111x; 1.2447x over previous
//
#include <hip/hip_runtime.h>
#include <hip/hip_bf16.h>

typedef __hip_bfloat16 bf16;
typedef __attribute__((ext_vector_type(8))) short bf16x8;
typedef __attribute__((ext_vector_type(8))) unsigned short u16x8;
typedef __attribute__((ext_vector_type(4))) float f32x4;

__device__ __forceinline__ float b2f(unsigned short u) {
  return __uint_as_float(((unsigned)u) << 16);
}
__device__ __forceinline__ unsigned short f2b(float x) {
  bf16 h = __float2bfloat16(x);
  return *reinterpret_cast<unsigned short*>(&h);
}

// ---------------- dtype probe (flag=1 -> bf16 storage, 0 -> fp32) ----------------
__global__ void k_probe(const unsigned short* __restrict__ raw, int* __restrict__ flag) {
  __shared__ int sbad, snz;
  const int t = threadIdx.x;
  if (t == 0) { sbad = 0; snz = 0; }
  __syncthreads();
  const unsigned short u = raw[t];
  const float a = fabsf(b2f(u));
  if (!(a < 100.f)) atomicAdd(&sbad, 1);
  if (((t & 1) == 0) && u != 0) atomicAdd(&snz, 1);
  __syncthreads();
  if (t == 0) flag[0] = (sbad == 0 && snz > 0) ? 1 : 0;
}

// ============== LDS counting-sort CSR build (no global atomics) ==============
// passA: per-(coarse bucket, chunk-block) counts. 256 blocks, bucket = dst>>8.
__global__ void k_passA(const int* __restrict__ dst, int E, int nbuck,
                        int* __restrict__ counts) {
  extern __shared__ int lh[];  // nbuck ints
  const int t = threadIdx.x;
  for (int k = t; k < nbuck; k += 256) lh[k] = 0;
  __syncthreads();
  const int chunk = (E + 255) / 256;
  const int s = blockIdx.x * chunk;
  const int e = min(E, s + chunk);
  for (int i = s + t; i < e; i += 256) atomicAdd(&lh[dst[i] >> 8], 1);
  __syncthreads();
  for (int k = t; k < nbuck; k += 256) counts[k * 256 + blockIdx.x] = lh[k];
}

// scan over M = nbuck*256 ints (in place), 256-elem chunks
__global__ void k_scan1(const int* __restrict__ a, int M, int* __restrict__ bsums) {
  __shared__ int sdata[256];
  int i = blockIdx.x * 256 + threadIdx.x;
  int v = (i < M) ? a[i] : 0;
  sdata[threadIdx.x] = v;
  __syncthreads();
  for (int s = 128; s > 0; s >>= 1) {
    if (threadIdx.x < s) sdata[threadIdx.x] += sdata[threadIdx.x + s];
    __syncthreads();
  }
  if (threadIdx.x == 0) bsums[blockIdx.x] = sdata[0];
}

__global__ void k_scan2(int* __restrict__ bsums, int nb, int* __restrict__ rowStart,
                        int N, int E) {
  __shared__ int s[512];
  const int t = threadIdx.x;
  const int v = (t < nb) ? bsums[t] : 0;
  s[t] = v;
  __syncthreads();
  for (int off = 1; off < 512; off <<= 1) {
    int u = (t >= off) ? s[t - off] : 0;
    __syncthreads();
    s[t] += u;
    __syncthreads();
  }
  if (t < nb) bsums[t] = s[t] - v;  // exclusive
  if (t == 0) rowStart[N] = E;
}

__global__ void k_scan3(int* __restrict__ a, int M, const int* __restrict__ bsums) {
  __shared__ int sdata[256];
  int i = blockIdx.x * 256 + threadIdx.x;
  int v = (i < M) ? a[i] : 0;
  sdata[threadIdx.x] = v;
  __syncthreads();
  for (int off = 1; off < 256; off <<= 1) {
    int t = (threadIdx.x >= off) ? sdata[threadIdx.x - off] : 0;
    __syncthreads();
    sdata[threadIdx.x] += t;
    __syncthreads();
  }
  if (i < M) a[i] = bsums[blockIdx.x] + sdata[threadIdx.x] - v;  // exclusive
}

// passC: scatter packed (src | (dst&255)<<20) into coarse-bucket-grouped tmp
__global__ void k_passC(const int* __restrict__ src, const int* __restrict__ dst, int E,
                        int nbuck, const int* __restrict__ S, int* __restrict__ tmp) {
  extern __shared__ int cur[];  // nbuck ints
  const int t = threadIdx.x;
  for (int k = t; k < nbuck; k += 256) cur[k] = S[k * 256 + blockIdx.x];
  __syncthreads();
  const int chunk = (E + 255) / 256;
  const int s = blockIdx.x * chunk;
  const int e = min(E, s + chunk);
  for (int i = s + t; i < e; i += 256) {
    const int d = dst[i];
    const int pos = atomicAdd(&cur[d >> 8], 1);
    tmp[pos] = src[i] | ((d & 255) << 20);
  }
}

// passD: per-bucket build: deg_in + rowStart coalesced, edgeSrc final scatter
__global__ void k_passD(const int* __restrict__ tmp, const int* __restrict__ S,
                        int nbuck, int N, int E, int* __restrict__ deg_in,
                        int* __restrict__ rowStart, int* __restrict__ edgeSrc) {
  __shared__ int h[256];
  __shared__ int ex[256];
  __shared__ int c[256];
  const int t = threadIdx.x;
  const int k = blockIdx.x;
  const int bs = S[k * 256];
  const int be = (k + 1 < nbuck) ? S[(k + 1) * 256] : E;
  h[t] = 0;
  __syncthreads();
  for (int i = bs + t; i < be; i += 256) atomicAdd(&h[tmp[i] >> 20], 1);
  __syncthreads();
  const int node = k * 256 + t;
  const int cnt = h[t];
  if (node < N) deg_in[node] = cnt;
  // exclusive scan of h
  ex[t] = cnt;
  __syncthreads();
  for (int off = 1; off < 256; off <<= 1) {
    int u = (t >= off) ? ex[t - off] : 0;
    __syncthreads();
    ex[t] += u;
    __syncthreads();
  }
  const int excl = ex[t] - cnt;
  if (node < N) rowStart[node] = bs + excl;
  c[t] = bs + excl;
  __syncthreads();
  for (int i = bs + t; i < be; i += 256) {
    const int v = tmp[i];
    const int pos = atomicAdd(&c[v >> 20], 1);
    edgeSrc[pos] = v & 0xFFFFF;
  }
}

// ---------------- norms ----------------
__global__ void k_norms(const int* __restrict__ deg_out, const int* __restrict__ deg_in, int N,
                        float* __restrict__ ns, float* __restrict__ nd) {
  int i = blockIdx.x * blockDim.x + threadIdx.x;
  if (i < N) {
    int dov = deg_out[i]; if (dov <= 0) dov = 1;
    int div = deg_in[i];  if (div <= 0) div = 1;
    ns[i] = rsqrtf((float)dov);
    nd[i] = rsqrtf((float)div);
  }
}

// ---------------- row-scale proj by norm_src ----------------
__global__ void k_scale(unsigned short* __restrict__ proj, const float* __restrict__ ns, int N) {
  int idx = blockIdx.x * blockDim.x + threadIdx.x;  // N*8 items of 8 elems
  if (idx < N * 8) {
    const int node = idx >> 3;
    const float f = ns[node];
    u16x8* p = (u16x8*)(proj + (size_t)node * 64 + (idx & 7) * 8);
    u16x8 v = *p;
#pragma unroll
    for (int j = 0; j < 8; ++j) v[j] = f2b(b2f(v[j]) * f);
    *p = v;
  }
}

// ---------------- MFMA GEMM (pure): out[r][c] = bf16( sum_k h[r][k]*W[k][c] ) ------
// 16x16x32 bf16 MFMA; A[m=lane&15][k=quad*8+j]; B[k][n=lane&15]; D col=lane&15,row=quad*4+reg
// HIST: blocks >= gemmBlocks do a deg_out histogram (atomics drain on fabric while
// gemm blocks compute -> cost ~ max(gemm, atomics) not sum).
template <int K, bool FIRST, bool HIST>
__global__ void k_gemm(const void* __restrict__ hin, const void* __restrict__ Wv,
                       const int* __restrict__ flag, int N,
                       unsigned short* __restrict__ out, int gemmBlocks,
                       const int* __restrict__ src, int E, int* __restrict__ deg_out) {
  if (HIST && blockIdx.x >= gemmBlocks) {
    const int hb = blockIdx.x - gemmBlocks;
    const int stride = 512 * 256;
    for (int i = hb * 256 + (int)threadIdx.x; i < E; i += stride)
      atomicAdd(&deg_out[src[i]], 1);
    return;
  }
  const bool isb = (*flag != 0);
  const int lane = threadIdx.x & 63;
  const int quad = lane >> 4;
  const int l16 = lane & 15;
  constexpr int KT = K / 32;

  bf16x8 Bf[KT][4];
  {
    const unsigned short* Wus = (const unsigned short*)Wv;
    const float* Wf = (const float*)Wv;
#pragma unroll
    for (int kt = 0; kt < KT; ++kt)
#pragma unroll
      for (int nt = 0; nt < 4; ++nt)
#pragma unroll
        for (int j = 0; j < 8; ++j) {
          const int k = kt * 32 + quad * 8 + j;
          const int n = nt * 16 + l16;
          const float w = isb ? b2f(Wus[k * 64 + n]) : Wf[k * 64 + n];
          Bf[kt][nt][j] = (short)f2b(w);
        }
  }

  const int wid = (blockIdx.x * blockDim.x + threadIdx.x) >> 6;
  const int nw = (gemmBlocks * 256) >> 6;
  const int G = (N + 15) >> 4;
  for (int g = wid; g < G; g += nw) {
    int rowA = (g << 4) + l16;
    if (rowA >= N) rowA = N - 1;
    f32x4 acc[4] = {{0.f, 0.f, 0.f, 0.f}, {0.f, 0.f, 0.f, 0.f},
                    {0.f, 0.f, 0.f, 0.f}, {0.f, 0.f, 0.f, 0.f}};
#pragma unroll
    for (int kt = 0; kt < KT; ++kt) {
      const int koff = kt * 32 + quad * 8;
      bf16x8 Af;
      if (FIRST && !isb) {
        const float* hp = (const float*)hin + (size_t)rowA * K + koff;
        const float4 u0 = *(const float4*)hp;
        const float4 u1 = *(const float4*)(hp + 4);
        Af[0] = (short)f2b(u0.x); Af[1] = (short)f2b(u0.y);
        Af[2] = (short)f2b(u0.z); Af[3] = (short)f2b(u0.w);
        Af[4] = (short)f2b(u1.x); Af[5] = (short)f2b(u1.y);
        Af[6] = (short)f2b(u1.z); Af[7] = (short)f2b(u1.w);
      } else {
        Af = *(const bf16x8*)((const unsigned short*)hin + (size_t)rowA * K + koff);
      }
      acc[0] = __builtin_amdgcn_mfma_f32_16x16x32_bf16(Af, Bf[kt][0], acc[0], 0, 0, 0);
      acc[1] = __builtin_amdgcn_mfma_f32_16x16x32_bf16(Af, Bf[kt][1], acc[1], 0, 0, 0);
      acc[2] = __builtin_amdgcn_mfma_f32_16x16x32_bf16(Af, Bf[kt][2], acc[2], 0, 0, 0);
      acc[3] = __builtin_amdgcn_mfma_f32_16x16x32_bf16(Af, Bf[kt][3], acc[3], 0, 0, 0);
    }
    const int rowD = (g << 4) + quad * 4;
#pragma unroll
    for (int r = 0; r < 4; ++r) {
      if (rowD + r < N) {
        const size_t o = (size_t)(rowD + r) * 64 + l16;
#pragma unroll
        for (int nt = 0; nt < 4; ++nt)
          out[o + nt * 16] = f2b(acc[nt][r]);
      }
    }
  }
}

// ---------------- aggregation: out[n] = relu(nd[n]*sum proj[src] + b) [* ns[n]] ----
template <bool LAST>
__global__ void k_aggregate(const unsigned short* __restrict__ proj,
                            const int* __restrict__ edgeSrc, const int* __restrict__ rowStart,
                            const float* __restrict__ norm_dst, const float* __restrict__ norm_src,
                            const void* __restrict__ bias, const int* __restrict__ flag,
                            int N, void* __restrict__ outp) {
  const bool isb = (*flag != 0);
  const int lane = threadIdx.x & 63;
  const int eo = lane >> 3;
  const int cg = lane & 7;
  float bcol[8];
#pragma unroll
  for (int j = 0; j < 8; ++j)
    bcol[j] = isb ? b2f(((const unsigned short*)bias)[cg * 8 + j])
                  : ((const float*)bias)[cg * 8 + j];
  const int wave = (blockIdx.x * blockDim.x + threadIdx.x) >> 6;
  const int nwaves = (gridDim.x * blockDim.x) >> 6;
  for (int n = wave; n < N; n += nwaves) {
    const int s = rowStart[n];
    int cnt = rowStart[n + 1] - s;
    float a[8] = {0.f, 0.f, 0.f, 0.f, 0.f, 0.f, 0.f, 0.f};
    int base = s;
    while (cnt > 0) {
      const int take = cnt < 64 ? cnt : 64;
      const int myIdx = (lane < take) ? edgeSrc[base + lane] : 0;
      for (int c = 0; c < take; c += 8) {
        const int sl = c + eo;
        const int sn = __shfl(myIdx, sl, 64);
        if (sl < take) {
          const u16x8 v = *(const u16x8*)(proj + (size_t)sn * 64 + cg * 8);
#pragma unroll
          for (int j = 0; j < 8; ++j) a[j] += b2f(v[j]);
        }
      }
      base += take;
      cnt -= take;
    }
#pragma unroll
    for (int j = 0; j < 8; ++j) {
      a[j] += __shfl_xor(a[j], 8, 64);
      a[j] += __shfl_xor(a[j], 16, 64);
      a[j] += __shfl_xor(a[j], 32, 64);
    }
    if (eo == 0) {
      const float nd = norm_dst[n];
      float r[8];
#pragma unroll
      for (int j = 0; j < 8; ++j) r[j] = fmaxf(fmaf(a[j], nd, bcol[j]), 0.f);
      if (!LAST) {
        const float esc = norm_src[n];  // pre-scale next layer's input rows
#pragma unroll
        for (int j = 0; j < 8; ++j) r[j] *= esc;
      }
      if (LAST && !isb) {
        float* of = (float*)outp + (size_t)n * 64 + cg * 8;
        float4 o0; o0.x = r[0]; o0.y = r[1]; o0.z = r[2]; o0.w = r[3];
        float4 o1; o1.x = r[4]; o1.y = r[5]; o1.z = r[6]; o1.w = r[7];
        *(float4*)of = o0;
        *(float4*)(of + 4) = o1;
      } else {
        u16x8 o;
#pragma unroll
        for (int j = 0; j < 8; ++j) o[j] = f2b(r[j]);
        *(u16x8*)((unsigned short*)outp + (size_t)n * 64 + cg * 8) = o;
      }
    }
  }
}

extern "C" void kernel_launch(void* const* d_in, const int* in_sizes, int n_in,
                              void* d_out, int out_size, void* d_ws, size_t ws_size,
                              hipStream_t stream) {
  const void* features = d_in[0];
  const void* W0 = d_in[1];
  const void* b0 = d_in[2];
  const void* W1 = d_in[3];
  const void* b1 = d_in[4];
  const void* W2 = d_in[5];
  const void* b2 = d_in[6];
  const int* src = (const int*)d_in[7];
  const int* dst = (const int*)d_in[8];
  const int N = in_sizes[0] / 128;
  const int E = in_sizes[7];
  const int NBUCK = (N + 255) >> 8;        // 391
  const int M = NBUCK * 256;               // counts size

  char* w = (char*)d_ws;
  size_t off = 0;
  auto alloc = [&](size_t bytes) {
    void* p = w + off;
    off = (off + bytes + 255) & ~(size_t)255;
    return p;
  };
  int* deg_out = (int*)alloc((size_t)N * 4);
  const size_t zero_bytes = off;  // only deg_out needs zeroing
  int* deg_in = (int*)alloc((size_t)N * 4);
  int* flag = (int*)alloc(4);
  int* rowStart = (int*)alloc((size_t)(N + 1) * 4);
  int* counts = (int*)alloc((size_t)M * 4);
  int* bsums = (int*)alloc(512 * 4);
  float* norm_src = (float*)alloc((size_t)N * 4);
  float* norm_dst = (float*)alloc((size_t)N * 4);
  int* tmp = (int*)alloc((size_t)E * 4);
  int* edgeSrc = (int*)alloc((size_t)E * 4);
  unsigned short* projA = (unsigned short*)alloc((size_t)N * 64 * 2);  // bf16
  unsigned short* hB = (unsigned short*)d_out;  // inter-layer h (bf16) in d_out

  hipMemsetAsync(d_ws, 0, zero_bytes, stream);
  k_probe<<<1, 256, 0, stream>>>((const unsigned short*)features, flag);

  const int GB = ((N + 15) / 16 + 3) / 4;  // gemm blocks (4 waves each)
  // gemm0 fused with deg_out histogram (512 extra blocks)
  k_gemm<128, true, true><<<GB + 512, 256, 0, stream>>>(
      features, W0, flag, N, projA, GB, src, E, deg_out);

  // CSR build: LDS counting sort, no global atomics
  const size_t lds_nb = (size_t)NBUCK * 4;
  k_passA<<<256, 256, lds_nb, stream>>>(dst, E, NBUCK, counts);
  const int NB2 = (M + 255) / 256;  // == NBUCK
  k_scan1<<<NB2, 256, 0, stream>>>(counts, M, bsums);
  k_scan2<<<1, 512, 0, stream>>>(bsums, NB2, rowStart, N, E);
  k_scan3<<<NB2, 256, 0, stream>>>(counts, M, bsums);
  k_passC<<<256, 256, lds_nb, stream>>>(src, dst, E, NBUCK, counts, tmp);
  k_passD<<<NBUCK, 256, 0, stream>>>(tmp, counts, NBUCK, N, E, deg_in, rowStart, edgeSrc);

  k_norms<<<(N + 255) / 256, 256, 0, stream>>>(deg_out, deg_in, N, norm_src, norm_dst);
  k_scale<<<(N * 8 + 255) / 256, 256, 0, stream>>>(projA, norm_src, N);

  const int AB = (N + 3) / 4;  // 1 wave/node
  // layer 0
  k_aggregate<false><<<AB, 256, 0, stream>>>(projA, edgeSrc, rowStart, norm_dst, norm_src, b0, flag, N, hB);
  // layer 1 (h pre-scaled by ns in agg epilogue)
  k_gemm<64, false, false><<<GB, 256, 0, stream>>>(hB, W1, flag, N, projA, GB, nullptr, 0, nullptr);
  k_aggregate<false><<<AB, 256, 0, stream>>>(projA, edgeSrc, rowStart, norm_dst, norm_src, b1, flag, N, hB);
  // layer 2 -> d_out
  k_gemm<64, false, false><<<GB, 256, 0, stream>>>(hB, W2, flag, N, projA, GB, nullptr, 0, nullptr);
  k_aggregate<true><<<AB, 256, 0, stream>>>(projA, edgeSrc, rowStart, norm_dst, norm_src, b2, flag, N, d_out);
}